// Round 1
// baseline (2533.428 us; speedup 1.0000x reference)
//
#include <hip/hip_runtime.h>

namespace {

constexpr int L  = 2048;
constexpr int Dh = 128;
constexpr int QB = 64;   // q-rows per workgroup
constexpr int KB = 64;   // k-cols per tile
constexpr float SCALE = 0.08838834764831845f;  // 1/sqrt(128)

typedef short  s16x8 __attribute__((ext_vector_type(8)));
typedef __bf16 bf16x8 __attribute__((ext_vector_type(8)));
typedef float  f32x4 __attribute__((ext_vector_type(4)));

__device__ inline unsigned short f2bf(float f) {
  unsigned u = __builtin_bit_cast(unsigned, f);
  return (unsigned short)((u + 0x7fffu + ((u >> 16) & 1u)) >> 16);  // RNE
}

// Stage a 64x128 fp32 tile from global -> bf16 LDS, row stride 256B,
// XOR-swizzled (byte ^= (row&7)<<4) to kill ds_read_b128 bank conflicts.
__device__ inline void stage64x128(const float* __restrict__ g, short* l, int tid) {
  #pragma unroll
  for (int i = 0; i < 4; ++i) {
    int c   = tid + i * 256;          // 1024 chunks of 8 elems
    int row = c >> 4;
    int d0  = (c & 15) * 8;
    const float4 f0 = *(const float4*)(g + row * Dh + d0);
    const float4 f1 = *(const float4*)(g + row * Dh + d0 + 4);
    s16x8 pk;
    pk[0] = (short)f2bf(f0.x); pk[1] = (short)f2bf(f0.y);
    pk[2] = (short)f2bf(f0.z); pk[3] = (short)f2bf(f0.w);
    pk[4] = (short)f2bf(f1.x); pk[5] = (short)f2bf(f1.y);
    pk[6] = (short)f2bf(f1.z); pk[7] = (short)f2bf(f1.w);
    int byte = (row * 256 + d0 * 2) ^ ((row & 7) << 4);
    *(s16x8*)((char*)l + byte) = pk;
  }
}

} // namespace

__global__ __launch_bounds__(256)
void sdpa_kernel(const float* __restrict__ Qg, const float* __restrict__ Kg,
                 const float* __restrict__ Vg, const int* __restrict__ Mg,
                 float* __restrict__ Og, float* __restrict__ Pg) {
  __shared__ __attribute__((aligned(16))) short lk[KB * Dh];    // K tile (row-major, swz)
  __shared__ __attribute__((aligned(16))) short lvt[Dh * KB];   // V^T tile (d-major, swz)
  __shared__ __attribute__((aligned(16))) short lq[QB * Dh];    // Q tile; reused as V row-major staging in pass 2
  __shared__ __attribute__((aligned(16))) short lp[4][16 * KB]; // per-wave P tile (bf16, swz)

  const int tid  = threadIdx.x;
  const int lane = tid & 63;
  const int wv   = tid >> 6;

  // bijective XCD-aware swizzle: 2048 blocks -> 8 chunks of 256 contiguous work items
  int id  = blockIdx.x;
  int nid = (id & 7) * 256 + (id >> 3);
  const int qt = nid & 31;
  const int bh = nid >> 5;
  const int b  = bh >> 4;
  const int q0 = qt * QB;

  const float* Qp = Qg + ((size_t)bh * L + q0) * Dh;
  const float* Kp = Kg + (size_t)bh * L * Dh;
  const float* Vp = Vg + (size_t)bh * L * Dh;
  const int*   Mp = Mg + (size_t)b * L * L + (size_t)q0 * L;
  float* Op = Og + ((size_t)bh * L + q0) * Dh;
  float* Pp = Pg + ((size_t)bh * L + q0) * L;

  stage64x128(Qp, lq, tid);
  __syncthreads();

  const int wr0 = wv * 16;
  const int lhi = lane >> 4;   // 0..3
  const int llo = lane & 15;   // 0..15

  // Preload Q A-frags: qf[ds][e] = Q[wr0+llo][ds*32 + lhi*8 + e]
  bf16x8 qf[4];
  {
    int row  = wr0 + llo;
    int base = row * 256;
    int sw   = (row & 7) << 4;
    #pragma unroll
    for (int ds = 0; ds < 4; ++ds) {
      int byte = (base + ds * 64 + lhi * 16) ^ sw;
      qf[ds] = __builtin_bit_cast(bf16x8, *(const s16x8*)((const char*)lq + byte));
    }
  }

  // Per-lane mask row pointers: this lane owns q-rows wr0 + lhi*4 + r (r=0..3)
  const int* mp[4];
  #pragma unroll
  for (int r = 0; r < 4; ++r)
    mp[r] = Mp + (size_t)(wr0 + lhi * 4 + r) * L + llo;

  float mreg[4], lreg[4];
  #pragma unroll
  for (int r = 0; r < 4; ++r) { mreg[r] = -__builtin_inff(); lreg[r] = 0.f; }

  const f32x4 zero4 = {0.f, 0.f, 0.f, 0.f};

  // ---------------- pass 1: per-row running max & sumexp ----------------
  for (int t = 0; t < L / KB; ++t) {
    const int k0 = t * KB;
    __syncthreads();                       // protect lk from previous tile's readers
    stage64x128(Kp + (size_t)k0 * Dh, lk, tid);
    __syncthreads();

    f32x4 sa[4];
    #pragma unroll
    for (int ct = 0; ct < 4; ++ct) sa[ct] = zero4;
    #pragma unroll
    for (int ds = 0; ds < 4; ++ds) {
      #pragma unroll
      for (int ct = 0; ct < 4; ++ct) {
        int row  = ct * 16 + llo;
        int byte = (row * 256 + ds * 64 + lhi * 16) ^ ((row & 7) << 4);
        bf16x8 kb = __builtin_bit_cast(bf16x8, *(const s16x8*)((const char*)lk + byte));
        sa[ct] = __builtin_amdgcn_mfma_f32_16x16x32_bf16(qf[ds], kb, sa[ct], 0, 0, 0);
      }
    }

    #pragma unroll
    for (int r = 0; r < 4; ++r) {
      int m0 = mp[r][k0];
      int m1 = mp[r][k0 + 16];
      int m2 = mp[r][k0 + 32];
      int m3 = mp[r][k0 + 48];
      float s0 = m0 ? sa[0][r] * SCALE : 1e-12f;
      float s1 = m1 ? sa[1][r] * SCALE : 1e-12f;
      float s2 = m2 ? sa[2][r] * SCALE : 1e-12f;
      float s3 = m3 ? sa[3][r] * SCALE : 1e-12f;
      float nm = fmaxf(fmaxf(fmaxf(s0, s1), fmaxf(s2, s3)), mreg[r]);
      lreg[r] = lreg[r] * __expf(mreg[r] - nm)
              + __expf(s0 - nm) + __expf(s1 - nm)
              + __expf(s2 - nm) + __expf(s3 - nm);
      mreg[r] = nm;
    }
  }

  // merge (m,l) across the 16 lanes sharing each q-row (butterfly within 16-lane group)
  float inv[4];
  #pragma unroll
  for (int r = 0; r < 4; ++r) {
    float m = mreg[r], l = lreg[r];
    #pragma unroll
    for (int off = 1; off < 16; off <<= 1) {
      float om = __shfl_xor(m, off);
      float ol = __shfl_xor(l, off);
      float nm = fmaxf(m, om);
      l = l * __expf(m - nm) + ol * __expf(om - nm);
      m = nm;
    }
    mreg[r] = m;
    inv[r]  = 1.f / l;
  }

  // ---------------- pass 2: write P, accumulate O = P*V ----------------
  f32x4 oa[8];
  #pragma unroll
  for (int dt = 0; dt < 8; ++dt) oa[dt] = zero4;

  short* lpw = &lp[wv][0];

  for (int t = 0; t < L / KB; ++t) {
    const int k0 = t * KB;
    __syncthreads();                        // prev tile's lk/lvt reads complete
    stage64x128(Kp + (size_t)k0 * Dh, lk, tid);
    stage64x128(Vp + (size_t)k0 * Dh, lq, tid);   // lq reused as V row-major staging
    __syncthreads();

    // transpose V: lq (64x128 row-major) -> lvt (128x64 d-major), both swizzled
    #pragma unroll
    for (int i = 0; i < 4; ++i) {
      int c  = tid + i * 256;     // 1024 chunks: (d 0..127) x (kc 0..7)
      int d  = c & 127;
      int kc = c >> 7;
      s16x8 pk;
      #pragma unroll
      for (int j = 0; j < 8; ++j) {
        int krow = kc * 8 + j;
        int byte = (krow * 256 + d * 2) ^ ((krow & 7) << 4);
        pk[j] = *(const short*)((const char*)lq + byte);
      }
      int ob = (d * 128 + kc * 16) ^ ((d & 7) << 4);
      *(s16x8*)((char*)lvt + ob) = pk;
    }

    // recompute S for this k-tile
    f32x4 sa[4];
    #pragma unroll
    for (int ct = 0; ct < 4; ++ct) sa[ct] = zero4;
    #pragma unroll
    for (int ds = 0; ds < 4; ++ds) {
      #pragma unroll
      for (int ct = 0; ct < 4; ++ct) {
        int row  = ct * 16 + llo;
        int byte = (row * 256 + ds * 64 + lhi * 16) ^ ((row & 7) << 4);
        bf16x8 kb = __builtin_bit_cast(bf16x8, *(const s16x8*)((const char*)lk + byte));
        sa[ct] = __builtin_amdgcn_mfma_f32_16x16x32_bf16(qf[ds], kb, sa[ct], 0, 0, 0);
      }
    }

    __syncthreads();                        // lvt ready for all waves

    // p = exp(s' - m) / l ; write fp32 to global P and bf16 to per-wave LDS
    #pragma unroll
    for (int r = 0; r < 4; ++r) {
      int row = lhi * 4 + r;
      float* prow = Pp + (size_t)(wr0 + row) * L + k0 + llo;
      #pragma unroll
      for (int ct = 0; ct < 4; ++ct) {
        int mv   = mp[r][k0 + ct * 16];
        float sv = mv ? sa[ct][r] * SCALE : 1e-12f;
        float p  = __expf(sv - mreg[r]) * inv[r];
        prow[ct * 16] = p;
        int col  = ct * 16 + llo;
        int byte = (row * 128 + col * 2) ^ ((row & 7) << 4);
        *(short*)((char*)lpw + byte) = (short)f2bf(p);
      }
    }

    asm volatile("s_waitcnt lgkmcnt(0)" ::: "memory");  // lp writes visible to this wave

    // O += P * V
    #pragma unroll
    for (int ks = 0; ks < 2; ++ks) {
      int abyte = (llo * 128 + ks * 64 + lhi * 16) ^ ((llo & 7) << 4);
      bf16x8 pa = __builtin_bit_cast(bf16x8, *(const s16x8*)((const char*)lpw + abyte));
      #pragma unroll
      for (int dt = 0; dt < 8; ++dt) {
        int drow  = dt * 16 + llo;
        int vbyte = (drow * 128 + ks * 64 + lhi * 16) ^ ((drow & 7) << 4);
        bf16x8 vb = __builtin_bit_cast(bf16x8, *(const s16x8*)((const char*)lvt + vbyte));
        oa[dt] = __builtin_amdgcn_mfma_f32_16x16x32_bf16(pa, vb, oa[dt], 0, 0, 0);
      }
    }
  }

  // write O (already normalized since P was normalized before PV)
  #pragma unroll
  for (int dt = 0; dt < 8; ++dt) {
    #pragma unroll
    for (int r = 0; r < 4; ++r) {
      int row = lhi * 4 + r;
      Op[(size_t)(wr0 + row) * Dh + dt * 16 + llo] = oa[dt][r];
    }
  }
}

extern "C" void kernel_launch(void* const* d_in, const int* in_sizes, int n_in,
                              void* d_out, int out_size, void* d_ws, size_t ws_size,
                              hipStream_t stream) {
  const float* Qg = (const float*)d_in[0];
  const float* Kg = (const float*)d_in[1];
  const float* Vg = (const float*)d_in[2];
  const int*   Mg = (const int*)d_in[3];
  float* Og = (float*)d_out;
  float* Pg = Og + (size_t)4 * 16 * L * Dh;   // out first, then attn_prob

  dim3 grid(2048);
  dim3 block(256);
  sdpa_kernel<<<grid, block, 0, stream>>>(Qg, Kg, Vg, Mg, Og, Pg);
}